// Round 4
// baseline (99.224 us; speedup 1.0000x reference)
//
#include <hip/hip_runtime.h>

#define NSAMP 2048
#define NCONF 128
#define NMO   64
#define NE    16   // electrons per spin (matrix dim)

// Block = 256 threads = 2 samples x 128 configs. The 2 samples' full MO block
// (2 x 32 x 64 floats = 16 KB) is staged coalesced into LDS once; each thread
// then gathers its 16x16 matrices from LDS (ds_read_b32, ~2-way bank alias).
//
// Per thread: det(up)*det(dn) via LEFT-LOOKING Householder QR -- column j is
// read from LDS only when processed; scaled reflectors V (lower-triangular,
// 136 floats) stay in registers. Peak live ~180 floats.
//
// (256,2): cap the unified VGPR+AGPR allocation at 256/wave -> 2 waves/SIMD.
// Round-3 A/B showed (256,1) let the allocator balloon past 256 total
// (OccupancyPercent 10%); the live set fits 256, so buy occupancy instead.
__global__ __launch_bounds__(256, 2)
void SlaterPooling_45543833207162_kernel(const float* __restrict__ x,
                                         const int*   __restrict__ cup,
                                         const int*   __restrict__ cdn,
                                         float*       __restrict__ out) {
  __shared__ float tile[2 * 2 * NE * NMO];   // [s_local][32 rows][64 cols]

  // ---- coalesced stage: 16 KB per block, 4 x float4 per thread ----
  {
    const float4* src = reinterpret_cast<const float4*>(
        x + (size_t)blockIdx.x * 2 * (2 * NE * NMO));
    float4* dst = reinterpret_cast<float4*>(tile);
#pragma unroll
    for (int k = 0; k < 4; ++k)
      dst[threadIdx.x + k * 256] = src[threadIdx.x + k * 256];
  }
  __syncthreads();

  const int s_local = threadIdx.x >> 7;        // 0..1
  const int c       = threadIdx.x & 127;       // config index
  const float* sbase = tile + s_local * (2 * NE * NMO);

  float result = 1.0f;

  // spin loop NOT unrolled: V and column regs reused across spins
#pragma unroll 1
  for (int spin = 0; spin < 2; ++spin) {
    const int*   cfg  = (spin ? cdn : cup) + c * NE;
    const float* base = sbase + spin * (NE * NMO);

    float V[NE - 1][NE];   // scaled reflector k in V[k][k..15]
    float det = -1.0f;     // (-1)^15 from 15 reflectors

#pragma unroll
    for (int j = 0; j < NE; ++j) {
      // ---- lazy gather of column j from LDS ----
      const int cj = cfg[j];
      float a[NE];
#pragma unroll
      for (int i = 0; i < NE; ++i) a[i] = base[i * NMO + cj];

      // ---- apply reflectors 0..j-1 (k<j folds at compile time) ----
#pragma unroll
      for (int k = 0; k < NE - 1; ++k) {
        if (k < j) {
          float w4[4] = {0.f, 0.f, 0.f, 0.f};
#pragma unroll
          for (int i = k; i < NE; ++i)
            w4[i & 3] = fmaf(V[k][i], a[i], w4[i & 3]);
          const float w = (w4[0] + w4[1]) + (w4[2] + w4[3]);
#pragma unroll
          for (int i = k; i < NE; ++i)
            a[i] = fmaf(-w, V[k][i], a[i]);
        }
      }

      // ---- form reflector j (or finish det on last column) ----
      if (j < NE - 1) {
        float s4[4] = {0.f, 0.f, 0.f, 0.f};
#pragma unroll
        for (int i = j; i < NE; ++i)
          s4[i & 3] = fmaf(a[i], a[i], s4[i & 3]);
        const float s2    = (s4[0] + s4[1]) + (s4[2] + s4[3]);
        const float nrm   = __builtin_amdgcn_sqrtf(s2);
        const float ajj   = a[j];
        const float alpha = (ajj >= 0.0f) ? -nrm : nrm;     // R_jj
        const float vk    = ajj - alpha;                    // no cancellation
        const float vtv   = 2.0f * fmaf(-alpha, ajj, s2);   // v^T v
        // pre-scale v by sqrt(2/v'v): H = I - v v^T, no tau needed later
        const float scale = 1.41421356237f * __builtin_amdgcn_rsqf(vtv);
        det *= alpha;
        V[j][j] = vk * scale;
#pragma unroll
        for (int i = j + 1; i < NE; ++i) V[j][i] = a[i] * scale;
      } else {
        det *= a[NE - 1];   // R[15][15]
      }
    }
    result *= det;
  }

  // out[s*128 + c]
  out[(blockIdx.x * 2 + s_local) * NCONF + c] = result;
}

extern "C" void kernel_launch(void* const* d_in, const int* in_sizes, int n_in,
                              void* d_out, int out_size, void* d_ws, size_t ws_size,
                              hipStream_t stream) {
  const float* x   = (const float*)d_in[0];
  const int*   cup = (const int*)d_in[1];
  const int*   cdn = (const int*)d_in[2];
  float*       out = (float*)d_out;

  dim3 grid(NSAMP / 2), block(256);   // 1024 blocks, 2 samples each
  hipLaunchKernelGGL(SlaterPooling_45543833207162_kernel, grid, block, 0, stream,
                     x, cup, cdn, out);
}

// Round 5
// 65.656 us; speedup vs baseline: 1.5113x; 1.5113x over previous
//
#include <hip/hip_runtime.h>

#define NSAMP 2048
#define NCONF 128
#define NMO   64
#define NE    16   // electrons per spin (matrix dim)

// 2-LANE COOPERATIVE left-looking Householder QR.
// Lanes 2t,2t+1 (parity p) share one (sample,config) det-pair; lane p owns
// matrix rows i == p (mod 2) (8 rows, local slot r <-> global row 2r+p).
// Column j is gathered from the LDS-staged sample when processed; scaled
// reflectors V (per-lane half: ~71 live floats) stay in registers.
// Cross-lane dot/norm = per-lane partial + one __shfl_xor(.,1) (DPP) + add.
// Scalars (s2, alpha, det) are computed redundantly in both lanes.
// Per-lane live ~100 floats -> (256,3) cap (~170 regs) has real headroom.
__global__ __launch_bounds__(256, 3)
void SlaterPooling_45543833207162_kernel(const float* __restrict__ x,
                                         const int*   __restrict__ cup,
                                         const int*   __restrict__ cdn,
                                         float*       __restrict__ out) {
  __shared__ float tile[2 * NE * NMO];   // one sample: 32 rows x 64 cols = 8 KB

  // ---- coalesced stage: 8 KB per block, 2 x float4 per thread ----
  {
    const float4* src = reinterpret_cast<const float4*>(
        x + (size_t)blockIdx.x * (2 * NE * NMO));
    float4* dst = reinterpret_cast<float4*>(tile);
#pragma unroll
    for (int k = 0; k < 2; ++k)
      dst[threadIdx.x + k * 256] = src[threadIdx.x + k * 256];
  }
  __syncthreads();

  const int p = threadIdx.x & 1;           // parity: which rows this lane owns
  const int c = (threadIdx.x >> 1) & 127;  // config index (one sample per block)

  float result = 1.0f;

  // spin loop NOT unrolled: V and column regs reused across spins
#pragma unroll 1
  for (int spin = 0; spin < 2; ++spin) {
    const int*   cfg  = (spin ? cdn : cup) + c * NE;
    const float* base = tile + spin * (NE * NMO);

    float V[NE - 1][8];   // scaled reflector k, this lane's rows; dead slots 0
    float det = -1.0f;    // (-1)^15 from 15 reflectors

#pragma unroll
    for (int j = 0; j < NE; ++j) {
      // ---- lazy gather of column j from LDS (this lane's 8 rows) ----
      const int cj = cfg[j];
      float a[8];
#pragma unroll
      for (int r = 0; r < 8; ++r)
        a[r] = base[(2 * r + p) * NMO + cj];

      // ---- apply reflectors 0..j-1 (k<j folds at compile time) ----
#pragma unroll
      for (int k = 0; k < NE - 1; ++k) {
        if (k < j) {
          float w0 = 0.f, w1 = 0.f;
#pragma unroll
          for (int r = 0; r < 8; ++r) {
            if (2 * r + 1 >= k) {        // slot live for at least one parity
              if (r & 1) w1 = fmaf(V[k][r], a[r], w1);
              else       w0 = fmaf(V[k][r], a[r], w0);
            }
          }
          const float wp = w0 + w1;
          const float w  = wp + __shfl_xor(wp, 1);
#pragma unroll
          for (int r = 0; r < 8; ++r) {
            if (2 * r + 1 >= k)
              a[r] = fmaf(-w, V[k][r], a[r]);
          }
        }
      }

      if (j < NE - 1) {
        // ---- norm over rows >= j ----
        float s0 = 0.f, s1 = 0.f;
#pragma unroll
        for (int r = 0; r < 8; ++r) {
          const int lo = 2 * r;
          if (lo >= j) {                 // rows lo+p >= j for both parities
            if (r & 1) s1 = fmaf(a[r], a[r], s1);
            else       s0 = fmaf(a[r], a[r], s0);
          } else if (lo + 1 == j) {      // included only when p==1
            const float t = p ? a[r] : 0.0f;
            s0 = fmaf(t, t, s0);
          }
        }
        const float sp = s0 + s1;
        const float s2 = sp + __shfl_xor(sp, 1);

        // ---- broadcast a[j] (diag) to both lanes ----
        const float cand  = a[j >> 1];          // correct in lane p == (j&1)
        const float other = __shfl_xor(cand, 1);
        const float ajj   = (j & 1) ? (p ? cand : other) : (p ? other : cand);

        const float nrm   = __builtin_amdgcn_sqrtf(s2);
        const float alpha = (ajj >= 0.0f) ? -nrm : nrm;     // R_jj
        const float vk    = ajj - alpha;                    // no cancellation
        const float vtv   = 2.0f * fmaf(-alpha, ajj, s2);   // v^T v
        const float sc    = 1.41421356237f * __builtin_amdgcn_rsqf(vtv);
        det *= alpha;

        // ---- store scaled reflector j (this lane's rows) ----
#pragma unroll
        for (int r = 0; r < 8; ++r) {
          const int lo = 2 * r;
          if (lo > j) {
            V[j][r] = a[r] * sc;                 // strictly below diag, both p
          } else if (lo == j) {                  // j even: p0=diag, p1=row j+1
            V[j][r] = (p ? a[r] : vk) * sc;
          } else if (lo + 1 == j) {              // j odd: p1=diag, p0=dead
            V[j][r] = (p ? vk : 0.0f) * sc;
          }
          // slots with 2r+1 < j are never read for reflector j
        }
      } else {
        // ---- last column: det *= R[15][15] = a[15] (lane p==1, slot 7) ----
        const float cand  = a[7];
        const float other = __shfl_xor(cand, 1);
        det *= (p ? cand : other);
      }
    }
    result *= det;
  }

  if (p == 0) out[blockIdx.x * NCONF + c] = result;   // out[s*128 + c]
}

extern "C" void kernel_launch(void* const* d_in, const int* in_sizes, int n_in,
                              void* d_out, int out_size, void* d_ws, size_t ws_size,
                              hipStream_t stream) {
  const float* x   = (const float*)d_in[0];
  const int*   cup = (const int*)d_in[1];
  const int*   cdn = (const int*)d_in[2];
  float*       out = (float*)d_out;

  dim3 grid(NSAMP), block(256);   // 1 sample x 128 configs x 2 lanes per block
  hipLaunchKernelGGL(SlaterPooling_45543833207162_kernel, grid, block, 0, stream,
                     x, cup, cdn, out);
}

// Round 6
// 45.991 us; speedup vs baseline: 2.1575x; 1.4276x over previous
//
#include <hip/hip_runtime.h>

#define NSAMP 2048
#define NCONF 128
#define NMO   64
#define NE    16   // electrons per spin (matrix dim)

// Block = 256 threads = 2 samples x 128 configs.
// The 2 samples' MO blocks are staged into LDS TRANSPOSED (column-major per
// (sample,spin) plane: 64 cols x 16 rows) with an XOR swizzle on the 16B slot
// index: word(c,r) = c*16 + ((r>>2 ^ h(c))<<2) + (r&3), h(c)=(c^(c>>2))&3.
// A matrix column is then 4 x ds_read_b128 (slots read in order q^h so the
// destination rows 4q..4q+3 are compile-time static -> registers). The
// swizzle spreads random-c column reads over 8 bank-slot groups (~2-way per
// 16-lane group = free); without it all columns start at bank 0 (32-way).
//
// Per thread: det(up)*det(dn) via LEFT-LOOKING Householder QR (round-3 code):
// column j read from LDS only when processed; scaled reflectors V
// (lower-triangular, 136 floats) stay in registers. (256,1): both (256,2)
// attempts spilled to scratch (rounds 2,4).
__global__ __launch_bounds__(256, 1)
void SlaterPooling_45543833207162_kernel(const float* __restrict__ x,
                                         const int*   __restrict__ cup,
                                         const int*   __restrict__ cdn,
                                         float*       __restrict__ out) {
  __shared__ float tile[4 * 64 * NE];   // 4 planes x 64 cols x 16 rows = 16 KB
  float4* tile4 = reinterpret_cast<float4*>(tile);

  // ---- stage 16 KB coalesced; write transposed + swizzled ----
  {
    const float4* src = reinterpret_cast<const float4*>(
        x + (size_t)blockIdx.x * 2 * (2 * NE * NMO));
#pragma unroll
    for (int k = 0; k < 4; ++k) {
      const int   f4 = threadIdx.x + k * 256;   // float4 index in block region
      const float4 v = src[f4];
      const int flat = f4 * 4;                  // word index (row-major global)
      const int plane = flat >> 10;             // (s_local, spin) plane 0..3
      const int r     = (flat >> 6) & 15;       // row within plane
      const int c4    = (flat >> 2) & 15;       // c = 4*c4 + d
      const int rlo = r & 3, rhi = r >> 2;
      const float vv[4] = {v.x, v.y, v.z, v.w};
#pragma unroll
      for (int d = 0; d < 4; ++d) {
        const int c = 4 * c4 + d;
        const int h = (d ^ c4) & 3;             // == (c ^ (c>>2)) & 3
        tile[plane * 1024 + c * NE + (((rhi ^ h) << 2) | rlo)] = vv[d];
      }
    }
  }
  __syncthreads();

  const int s_local = threadIdx.x >> 7;         // 0..1
  const int c       = threadIdx.x & 127;        // config index
  float result = 1.0f;

  // spin loop NOT unrolled: V and column regs reused across spins
#pragma unroll 1
  for (int spin = 0; spin < 2; ++spin) {
    // ---- config indices: 4 x int4, hoisted out of the column loop ----
    const int4* cfg4 = reinterpret_cast<const int4*>(
        (spin ? cdn : cup) + c * NE);
    const int4 w0 = cfg4[0], w1 = cfg4[1], w2 = cfg4[2], w3 = cfg4[3];
    const int cidx[16] = {w0.x, w0.y, w0.z, w0.w,  w1.x, w1.y, w1.z, w1.w,
                          w2.x, w2.y, w2.z, w2.w,  w3.x, w3.y, w3.z, w3.w};

    const float4* plane4 = tile4 + (s_local * 2 + spin) * 256;

    float V[NE - 1][NE];   // scaled reflector k in V[k][k..15]
    float det = -1.0f;     // (-1)^15 from 15 reflectors

#pragma unroll
    for (int j = 0; j < NE; ++j) {
      // ---- column j: 4 x ds_read_b128 from the swizzled plane ----
      const int cj = cidx[j];
      const int h  = (cj ^ (cj >> 2)) & 3;
      const float4* col = plane4 + cj * 4;
      float a[NE];
      { const float4 t = col[0 ^ h]; a[ 0]=t.x; a[ 1]=t.y; a[ 2]=t.z; a[ 3]=t.w; }
      { const float4 t = col[1 ^ h]; a[ 4]=t.x; a[ 5]=t.y; a[ 6]=t.z; a[ 7]=t.w; }
      { const float4 t = col[2 ^ h]; a[ 8]=t.x; a[ 9]=t.y; a[10]=t.z; a[11]=t.w; }
      { const float4 t = col[3 ^ h]; a[12]=t.x; a[13]=t.y; a[14]=t.z; a[15]=t.w; }

      // ---- apply reflectors 0..j-1 (k<j folds at compile time) ----
#pragma unroll
      for (int k = 0; k < NE - 1; ++k) {
        if (k < j) {
          float w4[4] = {0.f, 0.f, 0.f, 0.f};
#pragma unroll
          for (int i = k; i < NE; ++i)
            w4[i & 3] = fmaf(V[k][i], a[i], w4[i & 3]);
          const float w = (w4[0] + w4[1]) + (w4[2] + w4[3]);
#pragma unroll
          for (int i = k; i < NE; ++i)
            a[i] = fmaf(-w, V[k][i], a[i]);
        }
      }

      // ---- form reflector j (or finish det on last column) ----
      if (j < NE - 1) {
        float s4[4] = {0.f, 0.f, 0.f, 0.f};
#pragma unroll
        for (int i = j; i < NE; ++i)
          s4[i & 3] = fmaf(a[i], a[i], s4[i & 3]);
        const float s2    = (s4[0] + s4[1]) + (s4[2] + s4[3]);
        const float nrm   = __builtin_amdgcn_sqrtf(s2);
        const float ajj   = a[j];
        const float alpha = (ajj >= 0.0f) ? -nrm : nrm;     // R_jj
        const float vk    = ajj - alpha;                    // no cancellation
        const float vtv   = 2.0f * fmaf(-alpha, ajj, s2);   // v^T v
        // pre-scale v by sqrt(2/v'v): H = I - v v^T, no tau needed later
        const float scale = 1.41421356237f * __builtin_amdgcn_rsqf(vtv);
        det *= alpha;
        V[j][j] = vk * scale;
#pragma unroll
        for (int i = j + 1; i < NE; ++i) V[j][i] = a[i] * scale;
      } else {
        det *= a[NE - 1];   // R[15][15]
      }
    }
    result *= det;
  }

  // out[s*128 + c]
  out[(blockIdx.x * 2 + s_local) * NCONF + c] = result;
}

extern "C" void kernel_launch(void* const* d_in, const int* in_sizes, int n_in,
                              void* d_out, int out_size, void* d_ws, size_t ws_size,
                              hipStream_t stream) {
  const float* x   = (const float*)d_in[0];
  const int*   cup = (const int*)d_in[1];
  const int*   cdn = (const int*)d_in[2];
  float*       out = (float*)d_out;

  dim3 grid(NSAMP / 2), block(256);   // 1024 blocks, 2 samples each
  hipLaunchKernelGGL(SlaterPooling_45543833207162_kernel, grid, block, 0, stream,
                     x, cup, cdn, out);
}